// Round 12
// baseline (342.158 us; speedup 1.0000x reference)
//
#include <hip/hip_runtime.h>
#include <stdint.h>

#define B_ROWS 8192
#define DG 512
#define D2 768
#define D3 1024
#define DCAT 2304
#define DF 256
#define RANK 16
#define AH 512

// bf16 weight buffer element offsets
#define OFF_WG 0
#define OFF_W2 131072
#define OFF_W3 327680
#define OFF_U  589824
#define OFF_V  1638400
#define OFF_S  2686976
#define OFF_WA1 3735552

// workspace byte offsets (high-water ~90 MB; guard keeps proven 94,240,768)
// liveness: cvt{w:h*,wbuf} -> fatgemm{r:h*,wbuf; w:gbuf,a1p} -> post{r:a1p; w:beta}
//        -> rank_fused{r:gbuf,wbuf,beta; w:zpart} -> zsum{r:zpart; w:out}
#define WS_WBUF  0u            /*  9,830,400 B, alive whole run */
#define WS_HG    9830400u      /*  8,388,608 B bf16 h_g   (dead after fatgemm) */
#define WS_H2    18219008u     /* 12,582,912 B bf16 h_2d  (dead after fatgemm) */
#define WS_H3    30801920u     /* 16,777,216 B bf16 h_3d  (dead after fatgemm) */
#define WS_ZPART 9830400u      /* 4 x 8,388,608 B fp32; overlays dead h bufs */
#define WS_GBUF  47579136u     /* 12,582,912 B bf16, written by fatgemm epilogue */
#define WS_A1P   72744960u     /* 2 x 8,388,608 B bf16 split-K partials */
#define WS_BETA  89522176u     /*    524,288 B fp32 */
#define WS_REQUIRED 94240768u

typedef __attribute__((ext_vector_type(8))) short short8;
typedef __attribute__((ext_vector_type(4))) float f32x4;

__device__ inline unsigned short f2bf(float f) {
  union { float f; unsigned int u; } v; v.f = f;
  unsigned int u = v.u + 0x7fffu + ((v.u >> 16) & 1u);
  return (unsigned short)(u >> 16);
}
__device__ inline float bf2f(unsigned short h) {
  union { float f; unsigned int u; } v; v.u = ((unsigned int)h) << 16;
  return v.f;
}

typedef const unsigned int __attribute__((address_space(1)))* as1_u32p;
typedef unsigned int __attribute__((address_space(3)))* as3_u32p;

__device__ inline void g2l16(const unsigned short* g, unsigned short* l) {
  __builtin_amdgcn_global_load_lds((as1_u32p)g, (as3_u32p)l, 16, 0, 0);
}

// ---------------- streaming conversion (no interleave: 3 contiguous copies + weights) ----

__global__ __launch_bounds__(256) void cvt_split_k(const float* __restrict__ hg,
                                                   const float* __restrict__ h2,
                                                   const float* __restrict__ h3,
                                                   const float* __restrict__ Wg,
                                                   const float* __restrict__ W2,
                                                   const float* __restrict__ W3,
                                                   const float* __restrict__ U,
                                                   const float* __restrict__ V,
                                                   const float* __restrict__ S,
                                                   const float* __restrict__ Wa1,
                                                   unsigned short* __restrict__ hgb,
                                                   unsigned short* __restrict__ h2b,
                                                   unsigned short* __restrict__ h3b,
                                                   unsigned short* __restrict__ wbuf) {
  const int bid = blockIdx.x;
  const float* src;
  unsigned short* dst;
  int e;
  if (bid < 18432) {
    e = (bid * 256 + threadIdx.x) * 4;            // [0, 18874368)
    if (e < 4194304)        { src = hg + e;            dst = hgb + e; }
    else if (e < 10485760)  { src = h2 + (e - 4194304); dst = h2b + (e - 4194304); }
    else                    { src = h3 + (e - 10485760); dst = h3b + (e - 10485760); }
  } else {
    e = ((bid - 18432) * 256 + threadIdx.x) * 4;  // [0, 4915200)
    dst = wbuf + e;
    if (e < OFF_W2)       src = Wg  + e;
    else if (e < OFF_W3)  src = W2  + (e - OFF_W2);
    else if (e < OFF_U)   src = W3  + (e - OFF_W3);
    else if (e < OFF_V)   src = U   + (e - OFF_U);
    else if (e < OFF_S)   src = V   + (e - OFF_V);
    else if (e < OFF_WA1) src = S   + (e - OFF_S);
    else                  src = Wa1 + (e - OFF_WA1);
  }
  float4 v = *(const float4*)src;
  ushort4 o;
  o.x = f2bf(v.x); o.y = f2bf(v.y); o.z = f2bf(v.z); o.w = f2bf(v.w);
  *(ushort4*)dst = o;
}

// ---------------- GEMM mainloop, 128x128 tile, BK=64 (verified R5/R8) ----------------
// Accumulates into caller-initialized acc (enables multi-segment K and the
// two-pass proj trick). 256 threads = 4 waves in 2x2, wave tile 64x64, 4x4
// fragments of v_mfma_f32_16x16x32_bf16, global_load_lds width-16 staging,
// XOR bank swizzle (SQ_LDS_BANK_CONFLICT measured 0 in R5/R8).

__device__ __forceinline__ void gemm_mainloop_acc(const unsigned short* Ag, int lda,
                                                  const unsigned short* Bg, int ldb,
                                                  int K,
                                                  unsigned short* lA, unsigned short* lB,
                                                  f32x4 acc[4][4]) {
  const int tid = threadIdx.x;
  const int lane = tid & 63;
  const int wr = tid >> 7;
  const int wc = (tid >> 6) & 1;
  const int row_s = tid >> 3;        // staging: 8 x 16B chunks per 64-elem row
  const int kc_s = (((tid & 7) ^ ((tid >> 3) & 7)) << 3);
  const int mbase = wr * 64 + (lane & 15);
  const int nbase = wc * 64 + (lane & 15);
  const int kq = lane >> 4;          // k-quad index within fragment
  const int h = lane & 7;            // row-dependent XOR key

  const int nsteps = K >> 6;
  for (int ks = 0; ks < nsteps; ++ks) {
    const int k0 = ks << 6;
    __syncthreads();
#pragma unroll
    for (int p = 0; p < 4; ++p) {
      const int row = p * 32 + row_s;
      const int lofs = (p * 256 + tid) * 8;
      g2l16(Ag + (size_t)row * lda + k0 + kc_s, lA + lofs);
      g2l16(Bg + (size_t)row * ldb + k0 + kc_s, lB + lofs);
    }
    __syncthreads();
#pragma unroll
    for (int kk = 0; kk < 2; ++kk) {
      const int kch = (kk << 2) + kq;
      const int ko = ((kch ^ h) << 3);
      short8 af[4], bfr[4];
#pragma unroll
      for (int t = 0; t < 4; ++t) {
        af[t]  = *(const short8*)(lA + (mbase + t * 16) * 64 + ko);
        bfr[t] = *(const short8*)(lB + (nbase + t * 16) * 64 + ko);
      }
#pragma unroll
      for (int ti = 0; ti < 4; ++ti)
#pragma unroll
        for (int tj = 0; tj < 4; ++tj)
          acc[ti][tj] = __builtin_amdgcn_mfma_f32_16x16x32_bf16(af[ti], bfr[tj], acc[ti][tj], 0, 0, 0);
    }
  }
}

__device__ __forceinline__ void zero_acc(f32x4 acc[4][4]) {
#pragma unroll
  for (int i = 0; i < 4; ++i)
#pragma unroll
    for (int j = 0; j < 4; ++j)
      acc[i][j] = (f32x4){0.f, 0.f, 0.f, 0.f};
}

// ---------------- fat GEMM ----------------
// blocks [0,192): proj+LN+ReLU fused. Each block = 128 rows x FULL 256 cols of
//   one modality, via two sequential verified-mainloop passes (n0=0,128) with
//   acc0/acc1 held in registers; epilogue does bias + LN (16-lane shuffle
//   reduce + cross-wave LDS combine) + ReLU + bf16 store direct to gbuf.
//   proj fp32 buffer eliminated.
// blocks [192,704): a1 segment split-K2 (hg+h2 | h3), bf16 partial stores.

__global__ __launch_bounds__(256) void fatgemm_k(const unsigned short* __restrict__ hgb,
                                                 const unsigned short* __restrict__ h2b,
                                                 const unsigned short* __restrict__ h3b,
                                                 const unsigned short* __restrict__ wbuf,
                                                 const float* __restrict__ bg,
                                                 const float* __restrict__ b2,
                                                 const float* __restrict__ b3,
                                                 const float* __restrict__ wg, const float* __restrict__ wbg,
                                                 const float* __restrict__ w2, const float* __restrict__ wb2,
                                                 const float* __restrict__ w3, const float* __restrict__ wb3,
                                                 unsigned short* __restrict__ gbuf,
                                                 unsigned short* __restrict__ a1part) {
  __shared__ __align__(16) unsigned short lA[128 * 64];
  __shared__ __align__(16) unsigned short lB[128 * 64];
  __shared__ float redsum[2][128];
  __shared__ float redsq[2][128];
  const int bid = blockIdx.x;
  const int lane = threadIdx.x & 63;
  const int wr = threadIdx.x >> 7, wc = (threadIdx.x >> 6) & 1;

  if (bid < 192) {
    // ---- proj + LN fused ----
    const int z = bid / 64;
    const int m0 = (bid - z * 64) * 128;
    const int Kz   = (z == 0) ? DG : (z == 1 ? D2 : D3);
    const unsigned short* Ab = (z == 0) ? hgb : (z == 1 ? h2b : h3b);
    const int woff = (z == 0) ? OFF_WG : (z == 1 ? OFF_W2 : OFF_W3);
    const float* bias = (z == 0) ? bg : (z == 1 ? b2 : b3);
    const float* lnw  = (z == 0) ? wg : (z == 1 ? w2 : w3);
    const float* lnb  = (z == 0) ? wbg : (z == 1 ? wb2 : wb3);

    f32x4 acc0[4][4], acc1[4][4];
    zero_acc(acc0); zero_acc(acc1);
    gemm_mainloop_acc(Ab + (size_t)m0 * Kz, Kz, wbuf + woff, Kz, Kz, lA, lB, acc0);
    gemm_mainloop_acc(Ab + (size_t)m0 * Kz, Kz, wbuf + woff + (size_t)128 * Kz, Kz, Kz, lA, lB, acc1);

    // per-lane column params (cols c0+tj*16 for pass0, +128 for pass1)
    const int c0 = wc * 64 + (lane & 15);
    float bv0[4], bv1[4], wv0[4], wv1[4], ob0[4], ob1[4];
#pragma unroll
    for (int tj = 0; tj < 4; ++tj) {
      const int c = c0 + tj * 16;
      bv0[tj] = bias[c];      bv1[tj] = bias[c + 128];
      wv0[tj] = lnw[c];       wv1[tj] = lnw[c + 128];
      ob0[tj] = lnb[c];       ob1[tj] = lnb[c + 128];
    }

    const int quad = lane >> 4;
    // bias add + row stats (this wave holds 128 of the 256 cols per row)
#pragma unroll
    for (int ti = 0; ti < 4; ++ti)
#pragma unroll
      for (int i = 0; i < 4; ++i) {
        float s = 0.f, q = 0.f;
#pragma unroll
        for (int tj = 0; tj < 4; ++tj) {
          float v = acc0[ti][tj][i] + bv0[tj];
          acc0[ti][tj][i] = v; s += v; q += v * v;
          float w = acc1[ti][tj][i] + bv1[tj];
          acc1[ti][tj][i] = w; s += w; q += w * w;
        }
#pragma unroll
        for (int m = 1; m < 16; m <<= 1) { s += __shfl_xor(s, m, 64); q += __shfl_xor(q, m, 64); }
        if ((lane & 15) == 0) {
          const int rl = wr * 64 + ti * 16 + quad * 4 + i;
          redsum[wc][rl] = s;
          redsq[wc][rl] = q;
        }
      }
    __syncthreads();

    unsigned short* gout = gbuf + (size_t)z * B_ROWS * DF;
    const float inv = 1.f / 256.f;
#pragma unroll
    for (int ti = 0; ti < 4; ++ti)
#pragma unroll
      for (int i = 0; i < 4; ++i) {
        const int rl = wr * 64 + ti * 16 + quad * 4 + i;
        const float S = redsum[0][rl] + redsum[1][rl];
        const float Q = redsq[0][rl] + redsq[1][rl];
        const float mean = S * inv;
        const float var = Q * inv - mean * mean;
        const float rs = rsqrtf(var + 1e-5f);
        unsigned short* orow = gout + (size_t)(m0 + rl) * DF;
#pragma unroll
        for (int tj = 0; tj < 4; ++tj) {
          const float v0 = fmaxf((acc0[ti][tj][i] - mean) * rs * wv0[tj] + ob0[tj], 0.f);
          const float v1 = fmaxf((acc1[ti][tj][i] - mean) * rs * wv1[tj] + ob1[tj], 0.f);
          orow[c0 + tj * 16] = f2bf(v0);
          orow[c0 + tj * 16 + 128] = f2bf(v1);
        }
      }
  } else {
    // ---- a1 segment split-K2: half0 = hg(512)+h2(768), half1 = h3(1024) ----
    const int t = bid - 192;
    const int half = t >> 8;
    const int local = t & 255;
    const int m0 = (local >> 2) << 7;
    const int n0 = (local & 3) << 7;
    f32x4 acc[4][4];
    zero_acc(acc);
    const unsigned short* Bb = wbuf + OFF_WA1 + (size_t)n0 * DCAT;
    if (half == 0) {
      gemm_mainloop_acc(hgb + (size_t)m0 * DG, DG, Bb, DCAT, DG, lA, lB, acc);
      gemm_mainloop_acc(h2b + (size_t)m0 * D2, D2, Bb + DG, DCAT, D2, lA, lB, acc);
    } else {
      gemm_mainloop_acc(h3b + (size_t)m0 * D3, D3, Bb + DG + D2, DCAT, D3, lA, lB, acc);
    }
    unsigned short* out = a1part + (size_t)half * (B_ROWS * AH);
    const int r0 = m0 + wr * 64 + ((lane >> 4) << 2);
    const int c0 = n0 + wc * 64 + (lane & 15);
#pragma unroll
    for (int ti = 0; ti < 4; ++ti)
#pragma unroll
      for (int tj = 0; tj < 4; ++tj)
#pragma unroll
        for (int i = 0; i < 4; ++i)
          out[(size_t)(r0 + ti * 16 + i) * AH + (c0 + tj * 16)] = f2bf(acc[ti][tj][i]);
  }
}

// ---------------- fused rank GEMMs: double-buffered BK=128 pipeline (R11, frozen) -------
// 92.3 us measured; four structural variants (R5/R8/R9/R11) all ~92-103 us —
// plateaued at the LDS-port/latency floor for this fusion shape at 2 waves/SIMD.

__global__ __launch_bounds__(256) void rank_fused_k(const unsigned short* __restrict__ gbuf,
                                                    const unsigned short* __restrict__ wbuf,
                                                    const float* __restrict__ beta,
                                                    float* __restrict__ zpart) {
  __shared__ __align__(16) unsigned short lA[2 * 128 * 128];  // 64 KB
  __shared__ __align__(16) unsigned short lB[2 * 128 * 128];  // 64 KB
  __shared__ float lbeta[4 * 128];
  const int m0 = blockIdx.x * 128;
  const int d0 = blockIdx.y * 128;        // output col base within DF
  const int rg = blockIdx.z * 4;          // rank group base
  const int tid = threadIdx.x;

  for (int i = tid; i < 512; i += 256) {
    const int rr = i >> 7, row = i & 127;
    lbeta[i] = beta[(size_t)(m0 + row) * RANK + rg + rr];
  }

  const int lane = tid & 63;
  const int wr = tid >> 7, wc = (tid >> 6) & 1;
  const int row_s = tid >> 4;        // 0..15: staging row within a 16-row phase
  const int kc_s = (((tid & 15) ^ ((tid >> 4) & 15)) << 3);
  const int mbase = wr * 64 + (lane & 15);
  const int nbase = wc * 64 + (lane & 15);
  const int kq = lane >> 4;
  const int h = lane & 15;           // row-dependent XOR key (row&15 == lane&15)
  const int lr0 = wr * 64 + ((lane >> 4) << 2);   // local row base

  auto stage = [&](int rr, int zi, int ks, unsigned short* dA, unsigned short* dB) {
    const unsigned short* Ag = gbuf + (size_t)zi * (B_ROWS * DF) + (size_t)m0 * DF + (ks << 7);
    const unsigned short* Bg = wbuf + OFF_U + (size_t)zi * 1048576
                             + (size_t)((rg + rr) * 256 + d0) * DF + (ks << 7);
#pragma unroll
    for (int q = 0; q < 8; ++q) {
      const int row = q * 16 + row_s;
      const int lofs = (q * 256 + tid) * 8;
      g2l16(Ag + (size_t)row * DF + kc_s, dA + lofs);
      g2l16(Bg + (size_t)row * DF + kc_s, dB + lofs);
    }
  };

  f32x4 zacc[4][4], prod[4][4], acc[4][4];
#pragma unroll
  for (int ti = 0; ti < 4; ++ti)
#pragma unroll
    for (int tj = 0; tj < 4; ++tj) {
      zacc[ti][tj] = (f32x4){0.f, 0.f, 0.f, 0.f};
      acc[ti][tj]  = (f32x4){0.f, 0.f, 0.f, 0.f};
    }

  auto compute = [&](const unsigned short* sA, const unsigned short* sB) {
#pragma unroll
    for (int kk = 0; kk < 4; ++kk) {
      const int kch = (kk << 2) + kq;          // 0..15
      const int ko = ((kch ^ h) << 3);
      short8 af[4], bfr[4];
#pragma unroll
      for (int t = 0; t < 4; ++t) {
        af[t]  = *(const short8*)(sA + (mbase + t * 16) * 128 + ko);
        bfr[t] = *(const short8*)(sB + (nbase + t * 16) * 128 + ko);
      }
#pragma unroll
      for (int ti = 0; ti < 4; ++ti)
#pragma unroll
        for (int tj = 0; tj < 4; ++tj)
          acc[ti][tj] = __builtin_amdgcn_mfma_f32_16x16x32_bf16(af[ti], bfr[tj], acc[ti][tj], 0, 0, 0);
    }
  };

  stage(0, 0, 0, lA, lB);                     // prologue: pass 0, ks=0 -> buf0
  for (int p = 0; p < 12; ++p) {
    const int rr = p / 3;
    const int zi = p - rr * 3;
    __syncthreads();                          // drains buf0 stage; buf1 free
    stage(rr, zi, 1, lA + 16384, lB + 16384); // ks=1 -> buf1
    compute(lA, lB);                          // ks=0 from buf0
    __syncthreads();                          // drains buf1 stage; buf0 free
    if (p + 1 < 12) {
      const int pn = p + 1;
      const int rrn = pn / 3;
      stage(rrn, pn - rrn * 3, 0, lA, lB);    // next pass ks=0 -> buf0
    }
    compute(lA + 16384, lB + 16384);          // ks=1 from buf1

    if (zi == 0) {
#pragma unroll
      for (int ti = 0; ti < 4; ++ti)
#pragma unroll
        for (int tj = 0; tj < 4; ++tj)
          prod[ti][tj] = acc[ti][tj];
    } else if (zi == 1) {
#pragma unroll
      for (int ti = 0; ti < 4; ++ti)
#pragma unroll
        for (int tj = 0; tj < 4; ++tj)
          prod[ti][tj] *= acc[ti][tj];
    } else {
#pragma unroll
      for (int ti = 0; ti < 4; ++ti) {
        const float4 b4 = *(const float4*)(lbeta + rr * 128 + lr0 + ti * 16);
        const float bv[4] = {b4.x, b4.y, b4.z, b4.w};
#pragma unroll
        for (int tj = 0; tj < 4; ++tj)
#pragma unroll
          for (int i = 0; i < 4; ++i)
            zacc[ti][tj][i] += prod[ti][tj][i] * acc[ti][tj][i] * bv[i];
      }
    }
#pragma unroll
    for (int ti = 0; ti < 4; ++ti)
#pragma unroll
      for (int tj = 0; tj < 4; ++tj)
        acc[ti][tj] = (f32x4){0.f, 0.f, 0.f, 0.f};
  }

  float* zp = zpart + (size_t)blockIdx.z * (B_ROWS * DF);
  const int c0 = d0 + wc * 64 + (lane & 15);
#pragma unroll
  for (int ti = 0; ti < 4; ++ti)
#pragma unroll
    for (int tj = 0; tj < 4; ++tj)
#pragma unroll
      for (int i = 0; i < 4; ++i)
        zp[(size_t)(m0 + lr0 + ti * 16 + i) * DF + (c0 + tj * 16)] = zacc[ti][tj][i];
}

// ---------------- deterministic partial sum: z = zpart0+zpart1+zpart2+zpart3 ----------

__global__ __launch_bounds__(256) void zsum_k(const float* __restrict__ zpart,
                                              float* __restrict__ z) {
  const int idx = blockIdx.x * 256 + threadIdx.x;   // one float4 per thread
  const size_t e = (size_t)idx * 4;
  const size_t stride = (size_t)B_ROWS * DF;
  float4 a = *(const float4*)(zpart + e);
  float4 b = *(const float4*)(zpart + stride + e);
  float4 c = *(const float4*)(zpart + 2 * stride + e);
  float4 d = *(const float4*)(zpart + 3 * stride + e);
  float4 o;
  o.x = (a.x + b.x) + (c.x + d.x);
  o.y = (a.y + b.y) + (c.y + d.y);
  o.z = (a.z + b.z) + (c.z + d.z);
  o.w = (a.w + b.w) + (c.w + d.w);
  *(float4*)(z + e) = o;
}

// ---------------- beta kernel: bias + relu + logits + softmax (sums bf16 halves) --------

__global__ __launch_bounds__(256) void beta_k(const unsigned short* __restrict__ a1part,
                                              const float* __restrict__ ba1,
                                              const float* __restrict__ Wa2,
                                              const float* __restrict__ ba2,
                                              float* __restrict__ beta) {
  __shared__ float lw[RANK * AH];  // 32 KB
  for (int i = threadIdx.x; i < RANK * AH / 4; i += 256)
    *(float4*)(lw + i * 4) = *(const float4*)(Wa2 + i * 4);
  __syncthreads();
  const int row = blockIdx.x * 4 + (threadIdx.x >> 6);
  const int lane = threadIdx.x & 63;
  const unsigned short* h0 = a1part + (size_t)row * AH + lane * 8;
  const unsigned short* h1 = h0 + (size_t)B_ROWS * AH;
  const uint4 p0 = *(const uint4*)h0;
  const uint4 p1 = *(const uint4*)h1;
  const unsigned int u0[4] = {p0.x, p0.y, p0.z, p0.w};
  const unsigned int u1[4] = {p1.x, p1.y, p1.z, p1.w};
  float4 ca = *(const float4*)(ba1 + lane * 8);
  float4 cb = *(const float4*)(ba1 + lane * 8 + 4);
  const float bias[8] = {ca.x, ca.y, ca.z, ca.w, cb.x, cb.y, cb.z, cb.w};
  float av[8];
#pragma unroll
  for (int j = 0; j < 4; ++j) {
    const float s0 = bf2f((unsigned short)(u0[j] & 0xffffu)) + bf2f((unsigned short)(u1[j] & 0xffffu));
    const float s1 = bf2f((unsigned short)(u0[j] >> 16)) + bf2f((unsigned short)(u1[j] >> 16));
    av[2 * j]     = fmaxf(s0 + bias[2 * j], 0.f);
    av[2 * j + 1] = fmaxf(s1 + bias[2 * j + 1], 0.f);
  }
  float lg[RANK];
#pragma unroll
  for (int r = 0; r < RANK; ++r) {
    const float* wrow = lw + r * AH + lane * 8;
    float4 wa = *(const float4*)wrow;
    float4 wb = *(const float4*)(wrow + 4);
    float p = av[0] * wa.x + av[1] * wa.y + av[2] * wa.z + av[3] * wa.w
            + av[4] * wb.x + av[5] * wb.y + av[6] * wb.z + av[7] * wb.w;
#pragma unroll
    for (int m = 1; m < 64; m <<= 1) p += __shfl_xor(p, m, 64);
    lg[r] = p + ba2[r];
  }
  float mx = lg[0];
#pragma unroll
  for (int r = 1; r < RANK; ++r) mx = fmaxf(mx, lg[r]);
  float den = 0.f;
#pragma unroll
  for (int r = 0; r < RANK; ++r) { lg[r] = __expf(lg[r] - mx); den += lg[r]; }
  const float inv = 1.f / den;
  if (lane < RANK) {
    float mine = 0.f;
#pragma unroll
    for (int r = 0; r < RANK; ++r) mine = (lane == r) ? lg[r] : mine;
    beta[(size_t)row * RANK + lane] = mine * inv;
  }
}

// ---------------- launch ----------------

extern "C" void kernel_launch(void* const* d_in, const int* in_sizes, int n_in,
                              void* d_out, int out_size, void* d_ws, size_t ws_size,
                              hipStream_t stream) {
  if (ws_size < (size_t)WS_REQUIRED) return;  // guard: clean fail if ws too small

  const float* h_g   = (const float*)d_in[0];
  const float* h_2d  = (const float*)d_in[1];
  const float* h_3d  = (const float*)d_in[2];
  const float* Wg    = (const float*)d_in[3];
  const float* bg    = (const float*)d_in[4];
  const float* W2    = (const float*)d_in[5];
  const float* b2    = (const float*)d_in[6];
  const float* W3    = (const float*)d_in[7];
  const float* b3    = (const float*)d_in[8];
  const float* ln_g_w = (const float*)d_in[9];
  const float* ln_g_b = (const float*)d_in[10];
  const float* ln_2_w = (const float*)d_in[11];
  const float* ln_2_b = (const float*)d_in[12];
  const float* ln_3_w = (const float*)d_in[13];
  const float* ln_3_b = (const float*)d_in[14];
  const float* U     = (const float*)d_in[15];
  const float* V     = (const float*)d_in[16];
  const float* S     = (const float*)d_in[17];
  const float* Wa1   = (const float*)d_in[18];
  const float* ba1   = (const float*)d_in[19];
  const float* Wa2   = (const float*)d_in[20];
  const float* ba2   = (const float*)d_in[21];

  char* ws = (char*)d_ws;
  unsigned short* wbuf   = (unsigned short*)(ws + WS_WBUF);
  unsigned short* hgb    = (unsigned short*)(ws + WS_HG);
  unsigned short* h2b    = (unsigned short*)(ws + WS_H2);
  unsigned short* h3b    = (unsigned short*)(ws + WS_H3);
  float*          zpart  = (float*)(ws + WS_ZPART);          // overlays dead h bufs
  unsigned short* gbuf   = (unsigned short*)(ws + WS_GBUF);
  unsigned short* a1part = (unsigned short*)(ws + WS_A1P);
  float*          beta   = (float*)(ws + WS_BETA);
  float* z = (float*)d_out;

  cvt_split_k<<<dim3(23232), dim3(256), 0, stream>>>(h_g, h_2d, h_3d,
                                                     Wg, W2, W3, U, V, S, Wa1,
                                                     hgb, h2b, h3b, wbuf);
  fatgemm_k<<<dim3(704), dim3(256), 0, stream>>>(hgb, h2b, h3b, wbuf,
                                                 bg, b2, b3,
                                                 ln_g_w, ln_g_b, ln_2_w, ln_2_b,
                                                 ln_3_w, ln_3_b, gbuf, a1part);
  beta_k<<<dim3(2048), dim3(256), 0, stream>>>(a1part, ba1, Wa2, ba2, beta);
  rank_fused_k<<<dim3(64, 2, 4), dim3(256), 0, stream>>>(gbuf, wbuf, beta, zpart);
  zsum_k<<<dim3(2048), dim3(256), 0, stream>>>(zpart, z);
}

// Round 13
// 321.643 us; speedup vs baseline: 1.0638x; 1.0638x over previous
//
#include <hip/hip_runtime.h>
#include <stdint.h>

#define B_ROWS 8192
#define DG 512
#define D2 768
#define D3 1024
#define DCAT 2304
#define DF 256
#define RANK 16
#define AH 512

// bf16 weight buffer element offsets
#define OFF_WG 0
#define OFF_W2 131072
#define OFF_W3 327680
#define OFF_U  589824
#define OFF_V  1638400
#define OFF_S  2686976
#define OFF_WA1 3735552

// workspace byte offsets (high-water ~90 MB; guard keeps proven 94,240,768)
#define WS_WBUF  0u
#define WS_HG    9830400u      /* 8,388,608 B bf16 h_g */
#define WS_H2    18219008u     /* 12,582,912 B bf16 h_2d */
#define WS_H3    30801920u     /* 16,777,216 B bf16 h_3d */
#define WS_GBUF  9830400u      /* overlays hg/h2/h3: dead after fatgemm */
#define WS_PROJ  47579136u
#define WS_A1P   72744960u     /* 2 x 8,388,608 B bf16 split-K partials */
#define WS_BETA  89522176u
#define WS_ZPART 47579136u     /* 4 x 8,388,608 B; overlays proj+a1p (dead before rank_fused) */
#define WS_REQUIRED 94240768u

typedef __attribute__((ext_vector_type(8))) short short8;
typedef __attribute__((ext_vector_type(4))) float f32x4;

__device__ inline unsigned short f2bf(float f) {
  union { float f; unsigned int u; } v; v.f = f;
  unsigned int u = v.u + 0x7fffu + ((v.u >> 16) & 1u);
  return (unsigned short)(u >> 16);
}
__device__ inline float bf2f(unsigned short h) {
  union { float f; unsigned int u; } v; v.u = ((unsigned int)h) << 16;
  return v.f;
}

typedef const unsigned int __attribute__((address_space(1)))* as1_u32p;
typedef unsigned int __attribute__((address_space(3)))* as3_u32p;

__device__ inline void g2l16(const unsigned short* g, unsigned short* l) {
  __builtin_amdgcn_global_load_lds((as1_u32p)g, (as3_u32p)l, 16, 0, 0);
}

// ---------------- streaming conversion (no interleave: 3 contiguous copies + weights) ----

__global__ __launch_bounds__(256) void cvt_split_k(const float* __restrict__ hg,
                                                   const float* __restrict__ h2,
                                                   const float* __restrict__ h3,
                                                   const float* __restrict__ Wg,
                                                   const float* __restrict__ W2,
                                                   const float* __restrict__ W3,
                                                   const float* __restrict__ U,
                                                   const float* __restrict__ V,
                                                   const float* __restrict__ S,
                                                   const float* __restrict__ Wa1,
                                                   unsigned short* __restrict__ hgb,
                                                   unsigned short* __restrict__ h2b,
                                                   unsigned short* __restrict__ h3b,
                                                   unsigned short* __restrict__ wbuf) {
  const int bid = blockIdx.x;
  const float* src;
  unsigned short* dst;
  int e;
  if (bid < 18432) {
    e = (bid * 256 + threadIdx.x) * 4;            // [0, 18874368)
    if (e < 4194304)        { src = hg + e;            dst = hgb + e; }
    else if (e < 10485760)  { src = h2 + (e - 4194304); dst = h2b + (e - 4194304); }
    else                    { src = h3 + (e - 10485760); dst = h3b + (e - 10485760); }
  } else {
    e = ((bid - 18432) * 256 + threadIdx.x) * 4;  // [0, 4915200)
    dst = wbuf + e;
    if (e < OFF_W2)       src = Wg  + e;
    else if (e < OFF_W3)  src = W2  + (e - OFF_W2);
    else if (e < OFF_U)   src = W3  + (e - OFF_W3);
    else if (e < OFF_V)   src = U   + (e - OFF_U);
    else if (e < OFF_S)   src = V   + (e - OFF_V);
    else if (e < OFF_WA1) src = S   + (e - OFF_S);
    else                  src = Wa1 + (e - OFF_WA1);
  }
  float4 v = *(const float4*)src;
  ushort4 o;
  o.x = f2bf(v.x); o.y = f2bf(v.y); o.z = f2bf(v.z); o.w = f2bf(v.w);
  *(ushort4*)dst = o;
}

// ---------------- GEMM mainloop, 128x128 tile, BK=64 (verified R5/R8) ----------------
// Accumulates into caller-initialized acc (enables multi-segment K).
// 256 threads = 4 waves in 2x2, wave tile 64x64, 4x4 fragments of
// v_mfma_f32_16x16x32_bf16, global_load_lds width-16 staging, XOR bank
// swizzle (SQ_LDS_BANK_CONFLICT measured 0 in R5/R8).

__device__ __forceinline__ void gemm_mainloop_acc(const unsigned short* Ag, int lda,
                                                  const unsigned short* Bg, int ldb,
                                                  int K,
                                                  unsigned short* lA, unsigned short* lB,
                                                  f32x4 acc[4][4]) {
  const int tid = threadIdx.x;
  const int lane = tid & 63;
  const int wr = tid >> 7;
  const int wc = (tid >> 6) & 1;
  const int row_s = tid >> 3;        // staging: 8 x 16B chunks per 64-elem row
  const int kc_s = (((tid & 7) ^ ((tid >> 3) & 7)) << 3);
  const int mbase = wr * 64 + (lane & 15);
  const int nbase = wc * 64 + (lane & 15);
  const int kq = lane >> 4;          // k-quad index within fragment
  const int h = lane & 7;            // row-dependent XOR key

  const int nsteps = K >> 6;
  for (int ks = 0; ks < nsteps; ++ks) {
    const int k0 = ks << 6;
    __syncthreads();
#pragma unroll
    for (int p = 0; p < 4; ++p) {
      const int row = p * 32 + row_s;
      const int lofs = (p * 256 + tid) * 8;
      g2l16(Ag + (size_t)row * lda + k0 + kc_s, lA + lofs);
      g2l16(Bg + (size_t)row * ldb + k0 + kc_s, lB + lofs);
    }
    __syncthreads();
#pragma unroll
    for (int kk = 0; kk < 2; ++kk) {
      const int kch = (kk << 2) + kq;
      const int ko = ((kch ^ h) << 3);
      short8 af[4], bfr[4];
#pragma unroll
      for (int t = 0; t < 4; ++t) {
        af[t]  = *(const short8*)(lA + (mbase + t * 16) * 64 + ko);
        bfr[t] = *(const short8*)(lB + (nbase + t * 16) * 64 + ko);
      }
#pragma unroll
      for (int ti = 0; ti < 4; ++ti)
#pragma unroll
        for (int tj = 0; tj < 4; ++tj)
          acc[ti][tj] = __builtin_amdgcn_mfma_f32_16x16x32_bf16(af[ti], bfr[tj], acc[ti][tj], 0, 0, 0);
    }
  }
}

__device__ __forceinline__ void zero_acc(f32x4 acc[4][4]) {
#pragma unroll
  for (int i = 0; i < 4; ++i)
#pragma unroll
    for (int j = 0; j < 4; ++j)
      acc[i][j] = (f32x4){0.f, 0.f, 0.f, 0.f};
}

// ---------------- fat GEMM ----------------
// Block order puts the LONG a1 blocks FIRST (bid 0..511, ~20 BK=64 K-steps)
// and the short proj blocks last (bid 512..895, 8-16 K-steps): with ~768
// concurrent block slots, the short proj work backfills behind the running
// a1 blocks, so makespan ~= T_a1 instead of T_proj + T_a1 (tail cut).
// a1: segment split-K2 (hg+h2 | h3), bf16 partial stores — deterministic.
// proj: fp32 store (LN applied by post_k).

__global__ __launch_bounds__(256) void fatgemm_k(const unsigned short* __restrict__ hgb,
                                                 const unsigned short* __restrict__ h2b,
                                                 const unsigned short* __restrict__ h3b,
                                                 const unsigned short* __restrict__ wbuf,
                                                 float* __restrict__ proj,
                                                 unsigned short* __restrict__ a1part) {
  __shared__ __align__(16) unsigned short lA[128 * 64];
  __shared__ __align__(16) unsigned short lB[128 * 64];
  const int bid = blockIdx.x;
  f32x4 acc[4][4];
  const int lane = threadIdx.x & 63;
  const int wr = threadIdx.x >> 7, wc = (threadIdx.x >> 6) & 1;
  zero_acc(acc);

  if (bid < 512) {
    // a1 segment split-K2: half0 = hg(512)+h2(768), half1 = h3(1024).
    // 2 halves x (64 m-tiles x 4 n-tiles), bf16 partial store.
    const int half = bid >> 8;
    const int local = bid & 255;
    const int m0 = (local >> 2) << 7;
    const int n0 = (local & 3) << 7;
    const unsigned short* Bb = wbuf + OFF_WA1 + (size_t)n0 * DCAT;
    if (half == 0) {
      gemm_mainloop_acc(hgb + (size_t)m0 * DG, DG, Bb, DCAT, DG, lA, lB, acc);
      gemm_mainloop_acc(h2b + (size_t)m0 * D2, D2, Bb + DG, DCAT, D2, lA, lB, acc);
    } else {
      gemm_mainloop_acc(h3b + (size_t)m0 * D3, D3, Bb + DG + D2, DCAT, D3, lA, lB, acc);
    }
    unsigned short* out = a1part + (size_t)half * (B_ROWS * AH);
    const int r0 = m0 + wr * 64 + ((lane >> 4) << 2);
    const int c0 = n0 + wc * 64 + (lane & 15);
#pragma unroll
    for (int ti = 0; ti < 4; ++ti)
#pragma unroll
      for (int tj = 0; tj < 4; ++tj)
#pragma unroll
        for (int i = 0; i < 4; ++i)
          out[(size_t)(r0 + ti * 16 + i) * AH + (c0 + tj * 16)] = f2bf(acc[ti][tj][i]);
  } else {
    // proj: z = (bid-512)/128, 64 m-tiles x 2 n-tiles
    const int b = bid - 512;
    const int z = b >> 7;
    const int local = b & 127;
    const int m0 = (local >> 1) << 7;
    const int n0 = (local & 1) << 7;
    const int Kz   = (z == 0) ? DG : (z == 1 ? D2 : D3);
    const unsigned short* Ab = (z == 0) ? hgb : (z == 1 ? h2b : h3b);
    const int woff = (z == 0) ? OFF_WG : (z == 1 ? OFF_W2 : OFF_W3);
    gemm_mainloop_acc(Ab + (size_t)m0 * Kz, Kz,
                      wbuf + woff + (size_t)n0 * Kz, Kz, Kz, lA, lB, acc);
    float* out = proj + (size_t)z * B_ROWS * DF;
    const int r0 = m0 + wr * 64 + ((lane >> 4) << 2);
    const int c0 = n0 + wc * 64 + (lane & 15);
#pragma unroll
    for (int ti = 0; ti < 4; ++ti)
#pragma unroll
      for (int tj = 0; tj < 4; ++tj)
#pragma unroll
        for (int i = 0; i < 4; ++i)
          out[(size_t)(r0 + ti * 16 + i) * DF + (c0 + tj * 16)] = acc[ti][tj][i];
  }
}

// ---------------- fused rank GEMMs: double-buffered BK=128 pipeline (R11, frozen) -------
// 92.3 us measured; four structural variants (R5/R8/R9/R11) all ~92-103 us —
// plateaued at the LDS-port/latency floor for this fusion shape at 2 waves/SIMD.

__global__ __launch_bounds__(256) void rank_fused_k(const unsigned short* __restrict__ gbuf,
                                                    const unsigned short* __restrict__ wbuf,
                                                    const float* __restrict__ beta,
                                                    float* __restrict__ zpart) {
  __shared__ __align__(16) unsigned short lA[2 * 128 * 128];  // 64 KB
  __shared__ __align__(16) unsigned short lB[2 * 128 * 128];  // 64 KB
  __shared__ float lbeta[4 * 128];
  const int m0 = blockIdx.x * 128;
  const int d0 = blockIdx.y * 128;        // output col base within DF
  const int rg = blockIdx.z * 4;          // rank group base
  const int tid = threadIdx.x;

  for (int i = tid; i < 512; i += 256) {
    const int rr = i >> 7, row = i & 127;
    lbeta[i] = beta[(size_t)(m0 + row) * RANK + rg + rr];
  }

  const int lane = tid & 63;
  const int wr = tid >> 7, wc = (tid >> 6) & 1;
  const int row_s = tid >> 4;        // 0..15: staging row within a 16-row phase
  const int kc_s = (((tid & 15) ^ ((tid >> 4) & 15)) << 3);
  const int mbase = wr * 64 + (lane & 15);
  const int nbase = wc * 64 + (lane & 15);
  const int kq = lane >> 4;
  const int h = lane & 15;           // row-dependent XOR key (row&15 == lane&15)
  const int lr0 = wr * 64 + ((lane >> 4) << 2);   // local row base

  auto stage = [&](int rr, int zi, int ks, unsigned short* dA, unsigned short* dB) {
    const unsigned short* Ag = gbuf + (size_t)zi * (B_ROWS * DF) + (size_t)m0 * DF + (ks << 7);
    const unsigned short* Bg = wbuf + OFF_U + (size_t)zi * 1048576
                             + (size_t)((rg + rr) * 256 + d0) * DF + (ks << 7);
#pragma unroll
    for (int q = 0; q < 8; ++q) {
      const int row = q * 16 + row_s;
      const int lofs = (q * 256 + tid) * 8;
      g2l16(Ag + (size_t)row * DF + kc_s, dA + lofs);
      g2l16(Bg + (size_t)row * DF + kc_s, dB + lofs);
    }
  };

  f32x4 zacc[4][4], prod[4][4], acc[4][4];
#pragma unroll
  for (int ti = 0; ti < 4; ++ti)
#pragma unroll
    for (int tj = 0; tj < 4; ++tj) {
      zacc[ti][tj] = (f32x4){0.f, 0.f, 0.f, 0.f};
      acc[ti][tj]  = (f32x4){0.f, 0.f, 0.f, 0.f};
    }

  auto compute = [&](const unsigned short* sA, const unsigned short* sB) {
#pragma unroll
    for (int kk = 0; kk < 4; ++kk) {
      const int kch = (kk << 2) + kq;          // 0..15
      const int ko = ((kch ^ h) << 3);
      short8 af[4], bfr[4];
#pragma unroll
      for (int t = 0; t < 4; ++t) {
        af[t]  = *(const short8*)(sA + (mbase + t * 16) * 128 + ko);
        bfr[t] = *(const short8*)(sB + (nbase + t * 16) * 128 + ko);
      }
#pragma unroll
      for (int ti = 0; ti < 4; ++ti)
#pragma unroll
        for (int tj = 0; tj < 4; ++tj)
          acc[ti][tj] = __builtin_amdgcn_mfma_f32_16x16x32_bf16(af[ti], bfr[tj], acc[ti][tj], 0, 0, 0);
    }
  };

  stage(0, 0, 0, lA, lB);                     // prologue: pass 0, ks=0 -> buf0
  for (int p = 0; p < 12; ++p) {
    const int rr = p / 3;
    const int zi = p - rr * 3;
    __syncthreads();                          // drains buf0 stage; buf1 free
    stage(rr, zi, 1, lA + 16384, lB + 16384); // ks=1 -> buf1
    compute(lA, lB);                          // ks=0 from buf0
    __syncthreads();                          // drains buf1 stage; buf0 free
    if (p + 1 < 12) {
      const int pn = p + 1;
      const int rrn = pn / 3;
      stage(rrn, pn - rrn * 3, 0, lA, lB);    // next pass ks=0 -> buf0
    }
    compute(lA + 16384, lB + 16384);          // ks=1 from buf1

    if (zi == 0) {
#pragma unroll
      for (int ti = 0; ti < 4; ++ti)
#pragma unroll
        for (int tj = 0; tj < 4; ++tj)
          prod[ti][tj] = acc[ti][tj];
    } else if (zi == 1) {
#pragma unroll
      for (int ti = 0; ti < 4; ++ti)
#pragma unroll
        for (int tj = 0; tj < 4; ++tj)
          prod[ti][tj] *= acc[ti][tj];
    } else {
#pragma unroll
      for (int ti = 0; ti < 4; ++ti) {
        const float4 b4 = *(const float4*)(lbeta + rr * 128 + lr0 + ti * 16);
        const float bv[4] = {b4.x, b4.y, b4.z, b4.w};
#pragma unroll
        for (int tj = 0; tj < 4; ++tj)
#pragma unroll
          for (int i = 0; i < 4; ++i)
            zacc[ti][tj][i] += prod[ti][tj][i] * acc[ti][tj][i] * bv[i];
      }
    }
#pragma unroll
    for (int ti = 0; ti < 4; ++ti)
#pragma unroll
      for (int tj = 0; tj < 4; ++tj)
        acc[ti][tj] = (f32x4){0.f, 0.f, 0.f, 0.f};
  }

  float* zp = zpart + (size_t)blockIdx.z * (B_ROWS * DF);
  const int c0 = d0 + wc * 64 + (lane & 15);
#pragma unroll
  for (int ti = 0; ti < 4; ++ti)
#pragma unroll
    for (int tj = 0; tj < 4; ++tj)
#pragma unroll
      for (int i = 0; i < 4; ++i)
        zp[(size_t)(m0 + lr0 + ti * 16 + i) * DF + (c0 + tj * 16)] = zacc[ti][tj][i];
}

// ---------------- deterministic partial sum: z = zpart0+zpart1+zpart2+zpart3 ----------

__global__ __launch_bounds__(256) void zsum_k(const float* __restrict__ zpart,
                                              float* __restrict__ z) {
  const int idx = blockIdx.x * 256 + threadIdx.x;   // one float4 per thread
  const size_t e = (size_t)idx * 4;
  const size_t stride = (size_t)B_ROWS * DF;
  float4 a = *(const float4*)(zpart + e);
  float4 b = *(const float4*)(zpart + stride + e);
  float4 c = *(const float4*)(zpart + 2 * stride + e);
  float4 d = *(const float4*)(zpart + 3 * stride + e);
  float4 o;
  o.x = (a.x + b.x) + (c.x + d.x);
  o.y = (a.y + b.y) + (c.y + d.y);
  o.z = (a.z + b.z) + (c.z + d.z);
  o.w = (a.w + b.w) + (c.w + d.w);
  *(float4*)(z + e) = o;
}

// ---------------- merged post-GEMM kernel ----------------
// blocks [0,6144): LN+ReLU on proj -> gbuf (bf16).
// blocks [6144,8192): bias+relu+logits+softmax -> beta (sums bf16 split-K halves).

__global__ __launch_bounds__(256) void post_k(const float* __restrict__ proj,
                                              const float* __restrict__ bg, const float* __restrict__ b2, const float* __restrict__ b3,
                                              const float* __restrict__ wg, const float* __restrict__ wbg,
                                              const float* __restrict__ w2, const float* __restrict__ wb2,
                                              const float* __restrict__ w3, const float* __restrict__ wb3,
                                              unsigned short* __restrict__ gout,
                                              const unsigned short* __restrict__ a1part,
                                              const float* __restrict__ ba1,
                                              const float* __restrict__ Wa2,
                                              const float* __restrict__ ba2,
                                              float* __restrict__ beta) {
  const int bid = blockIdx.x;
  if (bid < 6144) {
    const int gid = bid * 4 + (threadIdx.x >> 6);
    const int lane = threadIdx.x & 63;
    const int z = gid >> 13;
    const int row = gid & (B_ROWS - 1);
    const float* bias = z == 0 ? bg : (z == 1 ? b2 : b3);
    const float* lw = z == 0 ? wg : (z == 1 ? w2 : w3);
    const float* lb = z == 0 ? wbg : (z == 1 ? wb2 : wb3);
    const float* x = proj + (size_t)z * B_ROWS * DF + (size_t)row * DF + lane * 4;
    float4 v = *(const float4*)x;
    float4 bb = *(const float4*)(bias + lane * 4);
    v.x += bb.x; v.y += bb.y; v.z += bb.z; v.w += bb.w;
    float s = v.x + v.y + v.z + v.w;
    float q = v.x * v.x + v.y * v.y + v.z * v.z + v.w * v.w;
#pragma unroll
    for (int m = 1; m < 64; m <<= 1) { s += __shfl_xor(s, m, 64); q += __shfl_xor(q, m, 64); }
    const float mean = s * (1.f / DF);
    const float var = q * (1.f / DF) - mean * mean;
    const float rs = rsqrtf(var + 1e-5f);
    float4 w4 = *(const float4*)(lw + lane * 4);
    float4 b4 = *(const float4*)(lb + lane * 4);
    ushort4 o;
    o.x = f2bf(fmaxf((v.x - mean) * rs * w4.x + b4.x, 0.f));
    o.y = f2bf(fmaxf((v.y - mean) * rs * w4.y + b4.y, 0.f));
    o.z = f2bf(fmaxf((v.z - mean) * rs * w4.z + b4.z, 0.f));
    o.w = f2bf(fmaxf((v.w - mean) * rs * w4.w + b4.w, 0.f));
    *(ushort4*)(gout + (size_t)z * B_ROWS * DF + (size_t)row * DF + lane * 4) = o;
  } else {
    __shared__ float lw[RANK * AH];  // 32 KB
    for (int i = threadIdx.x; i < RANK * AH / 4; i += 256)
      *(float4*)(lw + i * 4) = *(const float4*)(Wa2 + i * 4);
    __syncthreads();
    const int row = (bid - 6144) * 4 + (threadIdx.x >> 6);
    const int lane = threadIdx.x & 63;
    const unsigned short* h0 = a1part + (size_t)row * AH + lane * 8;
    const unsigned short* h1 = h0 + (size_t)B_ROWS * AH;
    const uint4 p0 = *(const uint4*)h0;
    const uint4 p1 = *(const uint4*)h1;
    const unsigned int u0[4] = {p0.x, p0.y, p0.z, p0.w};
    const unsigned int u1[4] = {p1.x, p1.y, p1.z, p1.w};
    float4 ca = *(const float4*)(ba1 + lane * 8);
    float4 cb = *(const float4*)(ba1 + lane * 8 + 4);
    const float bias[8] = {ca.x, ca.y, ca.z, ca.w, cb.x, cb.y, cb.z, cb.w};
    float av[8];
#pragma unroll
    for (int j = 0; j < 4; ++j) {
      const float s0 = bf2f((unsigned short)(u0[j] & 0xffffu)) + bf2f((unsigned short)(u1[j] & 0xffffu));
      const float s1 = bf2f((unsigned short)(u0[j] >> 16)) + bf2f((unsigned short)(u1[j] >> 16));
      av[2 * j]     = fmaxf(s0 + bias[2 * j], 0.f);
      av[2 * j + 1] = fmaxf(s1 + bias[2 * j + 1], 0.f);
    }
    float lg[RANK];
#pragma unroll
    for (int r = 0; r < RANK; ++r) {
      const float* wrow = lw + r * AH + lane * 8;
      float4 wa = *(const float4*)wrow;
      float4 wb = *(const float4*)(wrow + 4);
      float p = av[0] * wa.x + av[1] * wa.y + av[2] * wa.z + av[3] * wa.w
              + av[4] * wb.x + av[5] * wb.y + av[6] * wb.z + av[7] * wb.w;
#pragma unroll
      for (int m = 1; m < 64; m <<= 1) p += __shfl_xor(p, m, 64);
      lg[r] = p + ba2[r];
    }
    float mx = lg[0];
#pragma unroll
    for (int r = 1; r < RANK; ++r) mx = fmaxf(mx, lg[r]);
    float den = 0.f;
#pragma unroll
    for (int r = 0; r < RANK; ++r) { lg[r] = __expf(lg[r] - mx); den += lg[r]; }
    const float inv = 1.f / den;
    if (lane < RANK) {
      float mine = 0.f;
#pragma unroll
      for (int r = 0; r < RANK; ++r) mine = (lane == r) ? lg[r] : mine;
      beta[(size_t)row * RANK + lane] = mine * inv;
    }
  }
}

// ---------------- launch ----------------

extern "C" void kernel_launch(void* const* d_in, const int* in_sizes, int n_in,
                              void* d_out, int out_size, void* d_ws, size_t ws_size,
                              hipStream_t stream) {
  if (ws_size < (size_t)WS_REQUIRED) return;  // guard: clean fail if ws too small

  const float* h_g   = (const float*)d_in[0];
  const float* h_2d  = (const float*)d_in[1];
  const float* h_3d  = (const float*)d_in[2];
  const float* Wg    = (const float*)d_in[3];
  const float* bg    = (const float*)d_in[4];
  const float* W2    = (const float*)d_in[5];
  const float* b2    = (const float*)d_in[6];
  const float* W3    = (const float*)d_in[7];
  const float* b3    = (const float*)d_in[8];
  const float* ln_g_w = (const float*)d_in[9];
  const float* ln_g_b = (const float*)d_in[10];
  const float* ln_2_w = (const float*)d_in[11];
  const float* ln_2_b = (const float*)d_in[12];
  const float* ln_3_w = (const float*)d_in[13];
  const float* ln_3_b = (const float*)d_in[14];
  const float* U     = (const float*)d_in[15];
  const float* V     = (const float*)d_in[16];
  const float* S     = (const float*)d_in[17];
  const float* Wa1   = (const float*)d_in[18];
  const float* ba1   = (const float*)d_in[19];
  const float* Wa2   = (const float*)d_in[20];
  const float* ba2   = (const float*)d_in[21];

  char* ws = (char*)d_ws;
  unsigned short* wbuf   = (unsigned short*)(ws + WS_WBUF);
  unsigned short* hgb    = (unsigned short*)(ws + WS_HG);
  unsigned short* h2b    = (unsigned short*)(ws + WS_H2);
  unsigned short* h3b    = (unsigned short*)(ws + WS_H3);
  unsigned short* gbuf   = (unsigned short*)(ws + WS_GBUF);  // overlays hX_bf (dead by then)
  float*          proj   = (float*)(ws + WS_PROJ);
  unsigned short* a1part = (unsigned short*)(ws + WS_A1P);
  float*          beta   = (float*)(ws + WS_BETA);
  float*          zpart  = (float*)(ws + WS_ZPART);          // overlays proj+a1part (dead by then)
  float* z = (float*)d_out;

  cvt_split_k<<<dim3(23232), dim3(256), 0, stream>>>(h_g, h_2d, h_3d,
                                                     Wg, W2, W3, U, V, S, Wa1,
                                                     hgb, h2b, h3b, wbuf);
  fatgemm_k<<<dim3(896), dim3(256), 0, stream>>>(hgb, h2b, h3b, wbuf, proj, a1part);
  post_k<<<dim3(8192), dim3(256), 0, stream>>>(proj, bg, b2, b3, ln_g_w, ln_g_b,
                                               ln_2_w, ln_2_b, ln_3_w, ln_3_b, gbuf,
                                               a1part, ba1, Wa2, ba2, beta);
  // proj and a1part are dead from here on; zpart overlays them.
  rank_fused_k<<<dim3(64, 2, 4), dim3(256), 0, stream>>>(gbuf, wbuf, beta, zpart);
  zsum_k<<<dim3(2048), dim3(256), 0, stream>>>(zpart, z);
}